// Round 3
// baseline (119.809 us; speedup 1.0000x reference)
//
#include <hip/hip_runtime.h>
#include <hip/hip_fp16.h>

#define NF 10
#define NH 64
#define NP 9

#define FT_N 4096            // 1-D table entries per feature
#define PT_N 256             // 2-D table entries per axis
#define TLO (-16.0f)
#define THI (6.0f)

#define NPAIR_PTS (NP * PT_N * PT_N)     // 589824
#define NFEAT_PTS (NF * FT_N)            // 40960
#define NBUILD    (NPAIR_PTS + NFEAT_PTS) // 630784 = 2464 * 256 exactly

// Branchless Abramowitz-Stegun 7.1.26 erf, abs err ~1e-6 in f32.
__device__ __forceinline__ float fast_erf(float v) {
    float ax = fabsf(v);
    float t  = __builtin_amdgcn_rcpf(fmaf(0.3275911f, ax, 1.0f));
    float p  = fmaf(1.061405429f, t, -1.453152027f);
    p = fmaf(p, t, 1.421413741f);
    p = fmaf(p, t, -0.284496736f);
    p = fmaf(p, t, 0.254829592f);
    p = p * t;
    float e = __expf(-ax * ax);
    float r = fmaf(-p, e, 1.0f);   // 1 - p*e
    return copysignf(r, v);
}

__device__ __forceinline__ float gelu_exact(float v) {
    return 0.5f * v * (1.0f + fast_erf(v * 0.70710678118654752f));
}

// ---- build all table grid points (f32): pair points then feature points
__global__ __launch_bounds__(256) void build_tabs(
    const float* __restrict__ w1f, const float* __restrict__ b1f,
    const float* __restrict__ w2f, const float* __restrict__ b2f,
    const float* __restrict__ w1p, const float* __restrict__ b1p,
    const float* __restrict__ w2p, const float* __restrict__ b2p,
    float* __restrict__ ptabv, float* __restrict__ ftabv)
{
    int t = blockIdx.x * 256 + threadIdx.x;
    if (t < NPAIR_PTS) {
        int p  = t >> 16;
        int i0 = (t >> 8) & (PT_N - 1);
        int j  = t & (PT_N - 1);
        const float dz = (THI - TLO) / (float)(PT_N - 1);
        float z0 = TLO + dz * (float)i0;   // wave-uniform
        float zf = TLO + dz * (float)j;    // per-lane
        float s = b2p[p];
        #pragma unroll 8
        for (int h = 0; h < NH; ++h) {
            float a = w1p[(2 * p + 0) * NH + h];
            float b = w1p[(2 * p + 1) * NH + h];
            float u = fmaf(z0, a, fmaf(zf, b, b1p[p * NH + h]));
            s = fmaf(gelu_exact(u), w2p[p * NH + h], s);
        }
        ptabv[t] = s;
    } else {
        int u = t - NPAIR_PTS;
        int f = u >> 12;
        int i = u & (FT_N - 1);
        const float dz = (THI - TLO) / (float)(FT_N - 1);
        float z = TLO + dz * (float)i;
        float s = b2f[f];
        #pragma unroll 8
        for (int h = 0; h < NH; ++h) {
            float v = fmaf(z, w1f[f * NH + h], b1f[f * NH + h]);
            s = fmaf(gelu_exact(v), w2f[f * NH + h], s);
        }
        ftabv[u] = s;
    }
}

// ---- repack: pair quads (fp16 half4) + feature pairs (float2)
__global__ __launch_bounds__(256) void repack_tabs(
    const float* __restrict__ ptabv, const float* __restrict__ ftabv,
    uint2* __restrict__ pq, float2* __restrict__ fq)
{
    int t = blockIdx.x * 256 + threadIdx.x;
    if (t < NPAIR_PTS) {
        int i = (t >> 8) & (PT_N - 1);
        int j = t & (PT_N - 1);
        if (i < PT_N - 1 && j < PT_N - 1) {
            float v00 = ptabv[t];
            float v01 = ptabv[t + 1];
            float v10 = ptabv[t + PT_N];
            float v11 = ptabv[t + PT_N + 1];
            union { __half2 h[2]; uint2 u; } cvt;
            cvt.h[0] = __floats2half2_rn(v00, v01);
            cvt.h[1] = __floats2half2_rn(v10, v11);
            pq[t] = cvt.u;
        }
    } else {
        int u = t - NPAIR_PTS;
        int i = u & (FT_N - 1);
        if (i < FT_N - 1)
            fq[u] = make_float2(ftabv[u], ftabv[u + 1]);
    }
}

// ---- main: per-row packed table lookups
__global__ __launch_bounds__(256) void siarm_main(
    const float* __restrict__ x,
    const float* __restrict__ rmean, const float* __restrict__ rstd,
    const int*  __restrict__ crpp,
    const float2* __restrict__ fq, const uint2* __restrict__ pq,
    float* __restrict__ out, int nrows)
{
    int r = blockIdx.x * 256 + threadIdx.x;
    if (r >= nrows) return;
    const int crp = crpp[0];

    const float2* xr = reinterpret_cast<const float2*>(x + (size_t)r * NF);
    float raw[NF];
    #pragma unroll
    for (int q = 0; q < NF / 2; ++q) {
        float2 v = xr[q];
        raw[2 * q] = v.x; raw[2 * q + 1] = v.y;
    }

    float z[NF];
    #pragma unroll
    for (int f = 0; f < NF; ++f) {
        float rv = raw[f];
        if (f == crp) rv = __logf(fmaxf(rv * 10.0f, 1e-6f));
        z[f] = (rv - rmean[f]) * __builtin_amdgcn_rcpf(rstd[f]);
    }

    float acc = 0.0f;

    // additive 1-D lookups: one 8B load each
    const float invf = (float)(FT_N - 1) / (THI - TLO);
    #pragma unroll
    for (int f = 0; f < NF; ++f) {
        float c = fminf(fmaxf((z[f] - TLO) * invf, 0.0f), (float)(FT_N - 2));
        float fi = floorf(c);
        float fr = c - fi;
        int i = (int)fi;
        float2 lh = fq[f * FT_N + i];
        acc += fmaf(fr, lh.y - lh.x, lh.x);
    }

    // pairwise 2-D bilinear: one 8B quad load each
    const float invp = (float)(PT_N - 1) / (THI - TLO);
    float c0 = fminf(fmaxf((z[0] - TLO) * invp, 0.0f), (float)(PT_N - 2));
    float f0 = floorf(c0);
    float fr0 = c0 - f0;
    int i0 = (int)f0;
    #pragma unroll
    for (int p = 0; p < NP; ++p) {
        float cf = fminf(fmaxf((z[p + 1] - TLO) * invp, 0.0f), (float)(PT_N - 2));
        float ff = floorf(cf);
        float frf = cf - ff;
        int jf = (int)ff;
        uint2 q = pq[(p << 16) + (i0 << 8) + jf];
        __half2 ha = *reinterpret_cast<const __half2*>(&q.x);  // v00, v01
        __half2 hb = *reinterpret_cast<const __half2*>(&q.y);  // v10, v11
        float2 fa = __half22float2(ha);
        float2 fb = __half22float2(hb);
        float lo = fmaf(frf, fa.y - fa.x, fa.x);
        float hi = fmaf(frf, fb.y - fb.x, fb.x);
        acc += fmaf(fr0, hi - lo, lo);
    }

    out[r] = acc;
}

// ---- fallback: direct compute, used only if ws too small (never expected)
__global__ __launch_bounds__(256) void siarm_direct(
    const float* __restrict__ x,
    const float* __restrict__ rmean, const float* __restrict__ rstd,
    const float* __restrict__ w1f, const float* __restrict__ b1f,
    const float* __restrict__ w2f, const float* __restrict__ b2f,
    const float* __restrict__ w1p, const float* __restrict__ b1p,
    const float* __restrict__ w2p, const float* __restrict__ b2p,
    const int*  __restrict__ crpp,
    float* __restrict__ out, int nrows)
{
    int r = blockIdx.x * 256 + threadIdx.x;
    if (r >= nrows) return;
    const int crp = crpp[0];
    const size_t base = (size_t)r * NF;

    float raw0 = x[base + 0];
    if (crp == 0) raw0 = __logf(fmaxf(raw0 * 10.0f, 1e-6f));
    const float z0 = (raw0 - rmean[0]) / rstd[0];

    float acc = b2f[0];
    {
        float s = 0.0f;
        #pragma unroll 8
        for (int h = 0; h < NH; ++h) {
            float t = fmaf(z0, w1f[h], b1f[h]);
            s = fmaf(gelu_exact(t), w2f[h], s);
        }
        acc += s;
    }
    #pragma unroll 1
    for (int f = 1; f < NF; ++f) {
        float raw = x[base + f];
        if (f == crp) raw = __logf(fmaxf(raw * 10.0f, 1e-6f));
        const float zf = (raw - rmean[f]) / rstd[f];

        float sa = 0.0f;
        #pragma unroll 8
        for (int h = 0; h < NH; ++h) {
            float t = fmaf(zf, w1f[f * NH + h], b1f[f * NH + h]);
            sa = fmaf(gelu_exact(t), w2f[f * NH + h], sa);
        }
        const int p = f - 1;
        float sp = 0.0f;
        #pragma unroll 8
        for (int h = 0; h < NH; ++h) {
            float t = fmaf(z0, w1p[(2 * p) * NH + h],
                      fmaf(zf, w1p[(2 * p + 1) * NH + h], b1p[p * NH + h]));
            sp = fmaf(gelu_exact(t), w2p[p * NH + h], sp);
        }
        acc += sa + b2f[f] + sp + b2p[p];
    }
    out[r] = acc;
}

extern "C" void kernel_launch(void* const* d_in, const int* in_sizes, int n_in,
                              void* d_out, int out_size, void* d_ws, size_t ws_size,
                              hipStream_t stream) {
    const float* x     = (const float*)d_in[0];
    const float* rmean = (const float*)d_in[1];
    const float* rstd  = (const float*)d_in[2];
    const float* w1f   = (const float*)d_in[3];
    const float* b1f   = (const float*)d_in[4];
    const float* w2f   = (const float*)d_in[5];
    const float* b2f   = (const float*)d_in[6];
    const float* w1p   = (const float*)d_in[7];
    const float* b1p   = (const float*)d_in[8];
    const float* w2p   = (const float*)d_in[9];
    const float* b2p   = (const float*)d_in[10];
    const int*   crp   = (const int*)d_in[11];
    float* out = (float*)d_out;

    int nrows = out_size;

    // ws layout: [ptabv f32][ftabv f32][pq half4][fq float2]
    const size_t ptabv_sz = (size_t)NPAIR_PTS * sizeof(float);   // 2.36 MB
    const size_t ftabv_sz = (size_t)NFEAT_PTS * sizeof(float);   // 164 KB
    const size_t pq_sz    = (size_t)NPAIR_PTS * sizeof(uint2);   // 4.72 MB
    const size_t fq_sz    = (size_t)NFEAT_PTS * sizeof(float2);  // 328 KB
    const size_t total_sz = ptabv_sz + ftabv_sz + pq_sz + fq_sz;

    if (ws_size >= total_sz) {
        char* w = (char*)d_ws;
        float*  ptabv = (float*)w;                       w += ptabv_sz;
        float*  ftabv = (float*)w;                       w += ftabv_sz;
        uint2*  pq    = (uint2*)w;                       w += pq_sz;
        float2* fq    = (float2*)w;

        hipLaunchKernelGGL(build_tabs, dim3(NBUILD / 256), dim3(256), 0, stream,
                           w1f, b1f, w2f, b2f, w1p, b1p, w2p, b2p, ptabv, ftabv);
        hipLaunchKernelGGL(repack_tabs, dim3(NBUILD / 256), dim3(256), 0, stream,
                           ptabv, ftabv, pq, fq);
        hipLaunchKernelGGL(siarm_main, dim3((nrows + 255) / 256), dim3(256), 0, stream,
                           x, rmean, rstd, crp, fq, pq, out, nrows);
    } else {
        hipLaunchKernelGGL(siarm_direct, dim3((nrows + 255) / 256), dim3(256), 0, stream,
                           x, rmean, rstd, w1f, b1f, w2f, b2f,
                           w1p, b1p, w2p, b2p, crp, out, nrows);
    }
}

// Round 4
// 102.093 us; speedup vs baseline: 1.1735x; 1.1735x over previous
//
#include <hip/hip_runtime.h>
#include <hip/hip_fp16.h>

#define NF 10
#define NH 64
#define NP 9

#define FT_N 1024
#define F_LO (-16.0f)
#define F_HI (6.0f)

#define PT 160                 // pair grid points per axis
#define Z0_LO (-6.5f)
#define Z0_HI (6.5f)
// zf range: pairs != 4 use [-6.5, 6.5]; pair 4 (CRP) uses [-14.5, 6.5]

#define NPAIR_PTS (NP * PT * PT)        // 230400
#define PAIR_BLOCKS (NP * (PT * PT / 256))  // 9*100 = 900
#define FEAT_BLOCKS (NF * FT_N / 256)       // 40

// Branchless Abramowitz-Stegun 7.1.26 erf, abs err ~1e-6 in f32.
__device__ __forceinline__ float fast_erf(float v) {
    float ax = fabsf(v);
    float t  = __builtin_amdgcn_rcpf(fmaf(0.3275911f, ax, 1.0f));
    float p  = fmaf(1.061405429f, t, -1.453152027f);
    p = fmaf(p, t, 1.421413741f);
    p = fmaf(p, t, -0.284496736f);
    p = fmaf(p, t, 0.254829592f);
    p = p * t;
    float e = __expf(-ax * ax);
    float r = fmaf(-p, e, 1.0f);   // 1 - p*e
    return copysignf(r, v);
}

__device__ __forceinline__ float gelu_exact(float v) {
    return 0.5f * v * (1.0f + fast_erf(v * 0.70710678118654752f));
}

// ---- build both tables; scatter-write packed layouts directly.
// pq[p][i][j] = half4 {v(i,j), v(i,j+1), v(i+1,j), v(i+1,j+1)}  (8B cells)
// fq[f][i]    = float2 {v(i), v(i+1)}
__global__ __launch_bounds__(256) void build_tabs(
    const float* __restrict__ w1f, const float* __restrict__ b1f,
    const float* __restrict__ w2f, const float* __restrict__ b2f,
    const float* __restrict__ w1p, const float* __restrict__ b1p,
    const float* __restrict__ w2p, const float* __restrict__ b2p,
    __half* __restrict__ pqh,      // viewed as half[NPAIR_PTS][4]
    float* __restrict__ fqf)       // viewed as float[NF*FT_N][2]
{
    int bx = blockIdx.x;
    if (bx < PAIR_BLOCKS) {
        int p = bx / 100;
        int t = (bx - p * 100) * 256 + threadIdx.x;   // 0..25599
        int i = t / PT;           // z0 index
        int j = t - i * PT;       // zf index
        const float dz0 = (Z0_HI - Z0_LO) / (float)(PT - 1);
        const float zflo = (p == 4) ? -14.5f : -6.5f;
        const float dzf  = ((p == 4) ? (6.5f - (-14.5f)) : 13.0f) / (float)(PT - 1);
        float z0 = Z0_LO + dz0 * (float)i;
        float zf = zflo + dzf * (float)j;
        float s = b2p[p];
        #pragma unroll 8
        for (int h = 0; h < NH; ++h) {
            float a = w1p[(2 * p + 0) * NH + h];
            float b = w1p[(2 * p + 1) * NH + h];
            float u = fmaf(z0, a, fmaf(zf, b, b1p[p * NH + h]));
            s = fmaf(gelu_exact(u), w2p[p * NH + h], s);
        }
        __half hv = __float2half_rn(s);
        // scatter into the 4 quads that reference grid point (i,j)
        size_t cell = (size_t)(p * PT + i) * PT + j;   // quad (p,i,j)
        if (i <= PT - 2 && j <= PT - 2) pqh[4 * cell + 0] = hv;                 // v00 of (i,j)
        if (i <= PT - 2 && j >= 1)      pqh[4 * (cell - 1) + 1] = hv;           // v01 of (i,j-1)
        if (i >= 1      && j <= PT - 2) pqh[4 * (cell - PT) + 2] = hv;          // v10 of (i-1,j)
        if (i >= 1      && j >= 1)      pqh[4 * (cell - PT - 1) + 3] = hv;      // v11 of (i-1,j-1)
    } else {
        int u = (bx - PAIR_BLOCKS) * 256 + threadIdx.x;  // 0..10239
        int f = u >> 10;
        int i = u & (FT_N - 1);
        const float dz = (F_HI - F_LO) / (float)(FT_N - 1);
        float z = F_LO + dz * (float)i;
        float s = b2f[f];
        #pragma unroll 8
        for (int h = 0; h < NH; ++h) {
            float v = fmaf(z, w1f[f * NH + h], b1f[f * NH + h]);
            s = fmaf(gelu_exact(v), w2f[f * NH + h], s);
        }
        if (i <= FT_N - 2) fqf[2 * u + 0] = s;       // fq[u].x
        if (i >= 1)        fqf[2 * (u - 1) + 1] = s; // fq[u-1].y
    }
}

// ---- main: per-row packed table lookups
__global__ __launch_bounds__(256) void siarm_main(
    const float* __restrict__ x,
    const float* __restrict__ rmean, const float* __restrict__ rstd,
    const int*  __restrict__ crpp,
    const float2* __restrict__ fq, const uint2* __restrict__ pq,
    float* __restrict__ out, int nrows)
{
    int r = blockIdx.x * 256 + threadIdx.x;
    if (r >= nrows) return;
    const int crp = crpp[0];

    const float2* xr = reinterpret_cast<const float2*>(x + (size_t)r * NF);
    float raw[NF];
    #pragma unroll
    for (int q = 0; q < NF / 2; ++q) {
        float2 v = xr[q];
        raw[2 * q] = v.x; raw[2 * q + 1] = v.y;
    }

    float z[NF];
    #pragma unroll
    for (int f = 0; f < NF; ++f) {
        float rv = raw[f];
        if (f == crp) rv = __logf(fmaxf(rv * 10.0f, 1e-6f));
        z[f] = (rv - rmean[f]) * __builtin_amdgcn_rcpf(rstd[f]);
    }

    float acc = 0.0f;

    // additive 1-D lookups: one 8B float2 load each
    const float invf = (float)(FT_N - 1) / (F_HI - F_LO);
    const float offf = -F_LO * invf;
    #pragma unroll
    for (int f = 0; f < NF; ++f) {
        float c = fminf(fmaxf(fmaf(z[f], invf, offf), 0.0f), (float)(FT_N - 2));
        float fi = floorf(c);
        float fr = c - fi;
        int i = (int)fi;
        float2 lh = fq[f * FT_N + i];
        acc += fmaf(fr, lh.y - lh.x, lh.x);
    }

    // pairwise 2-D bilinear: one 8B fp16-quad load each
    const float inv0 = (float)(PT - 1) / (Z0_HI - Z0_LO);
    const float off0 = -Z0_LO * inv0;
    float c0 = fminf(fmaxf(fmaf(z[0], inv0, off0), 0.0f), (float)(PT - 2));
    float f0 = floorf(c0);
    float fr0 = c0 - f0;
    int i0 = (int)f0;
    #pragma unroll
    for (int p = 0; p < NP; ++p) {
        const float zflo = (p == 4) ? -14.5f : -6.5f;
        const float invp_ = (float)(PT - 1) / ((p == 4) ? 21.0f : 13.0f);
        const float offp  = -zflo * invp_;
        float cf = fminf(fmaxf(fmaf(z[p + 1], invp_, offp), 0.0f), (float)(PT - 2));
        float ff = floorf(cf);
        float frf = cf - ff;
        int jf = (int)ff;
        uint2 q = pq[(size_t)(p * PT + i0) * PT + jf];
        __half2 ha = *reinterpret_cast<const __half2*>(&q.x);  // v00, v01
        __half2 hb = *reinterpret_cast<const __half2*>(&q.y);  // v10, v11
        float2 fa = __half22float2(ha);
        float2 fb = __half22float2(hb);
        float lo = fmaf(frf, fa.y - fa.x, fa.x);
        float hi = fmaf(frf, fb.y - fb.x, fb.x);
        acc += fmaf(fr0, hi - lo, lo);
    }

    out[r] = acc;
}

// ---- fallback: direct compute, used only if ws too small (never expected)
__global__ __launch_bounds__(256) void siarm_direct(
    const float* __restrict__ x,
    const float* __restrict__ rmean, const float* __restrict__ rstd,
    const float* __restrict__ w1f, const float* __restrict__ b1f,
    const float* __restrict__ w2f, const float* __restrict__ b2f,
    const float* __restrict__ w1p, const float* __restrict__ b1p,
    const float* __restrict__ w2p, const float* __restrict__ b2p,
    const int*  __restrict__ crpp,
    float* __restrict__ out, int nrows)
{
    int r = blockIdx.x * 256 + threadIdx.x;
    if (r >= nrows) return;
    const int crp = crpp[0];
    const size_t base = (size_t)r * NF;

    float raw0 = x[base + 0];
    if (crp == 0) raw0 = __logf(fmaxf(raw0 * 10.0f, 1e-6f));
    const float z0 = (raw0 - rmean[0]) / rstd[0];

    float acc = b2f[0];
    {
        float s = 0.0f;
        #pragma unroll 8
        for (int h = 0; h < NH; ++h) {
            float t = fmaf(z0, w1f[h], b1f[h]);
            s = fmaf(gelu_exact(t), w2f[h], s);
        }
        acc += s;
    }
    #pragma unroll 1
    for (int f = 1; f < NF; ++f) {
        float raw = x[base + f];
        if (f == crp) raw = __logf(fmaxf(raw * 10.0f, 1e-6f));
        const float zf = (raw - rmean[f]) / rstd[f];

        float sa = 0.0f;
        #pragma unroll 8
        for (int h = 0; h < NH; ++h) {
            float t = fmaf(zf, w1f[f * NH + h], b1f[f * NH + h]);
            sa = fmaf(gelu_exact(t), w2f[f * NH + h], sa);
        }
        const int p = f - 1;
        float sp = 0.0f;
        #pragma unroll 8
        for (int h = 0; h < NH; ++h) {
            float t = fmaf(z0, w1p[(2 * p) * NH + h],
                      fmaf(zf, w1p[(2 * p + 1) * NH + h], b1p[p * NH + h]));
            sp = fmaf(gelu_exact(t), w2p[p * NH + h], sp);
        }
        acc += sa + b2f[f] + sp + b2p[p];
    }
    out[r] = acc;
}

extern "C" void kernel_launch(void* const* d_in, const int* in_sizes, int n_in,
                              void* d_out, int out_size, void* d_ws, size_t ws_size,
                              hipStream_t stream) {
    const float* x     = (const float*)d_in[0];
    const float* rmean = (const float*)d_in[1];
    const float* rstd  = (const float*)d_in[2];
    const float* w1f   = (const float*)d_in[3];
    const float* b1f   = (const float*)d_in[4];
    const float* w2f   = (const float*)d_in[5];
    const float* b2f   = (const float*)d_in[6];
    const float* w1p   = (const float*)d_in[7];
    const float* b1p   = (const float*)d_in[8];
    const float* w2p   = (const float*)d_in[9];
    const float* b2p   = (const float*)d_in[10];
    const int*   crp   = (const int*)d_in[11];
    float* out = (float*)d_out;

    int nrows = out_size;

    const size_t pq_sz = (size_t)NPAIR_PTS * 8;           // fp16 quads, 1.84 MB
    const size_t fq_sz = (size_t)NF * FT_N * sizeof(float2); // 80 KB
    const size_t total_sz = pq_sz + fq_sz;

    if (ws_size >= total_sz) {
        char* w = (char*)d_ws;
        __half* pqh = (__half*)w;
        uint2*  pq  = (uint2*)w;
        float*  fqf = (float*)(w + pq_sz);
        float2* fq  = (float2*)(w + pq_sz);

        hipLaunchKernelGGL(build_tabs, dim3(PAIR_BLOCKS + FEAT_BLOCKS), dim3(256), 0, stream,
                           w1f, b1f, w2f, b2f, w1p, b1p, w2p, b2p, pqh, fqf);
        hipLaunchKernelGGL(siarm_main, dim3((nrows + 255) / 256), dim3(256), 0, stream,
                           x, rmean, rstd, crp, fq, pq, out, nrows);
    } else {
        hipLaunchKernelGGL(siarm_direct, dim3((nrows + 255) / 256), dim3(256), 0, stream,
                           x, rmean, rstd, w1f, b1f, w2f, b2f,
                           w1p, b1p, w2p, b2p, crp, out, nrows);
    }
}

// Round 5
// 92.227 us; speedup vs baseline: 1.2991x; 1.1070x over previous
//
#include <hip/hip_runtime.h>
#include <hip/hip_fp16.h>

#define NF 10
#define NH 64
#define NP 9

#define PT 28                 // pair grid points per axis
#define FT 64                 // 1-D grid points per feature
#define ZHI   (6.0f)
#define ZLO_N (-6.0f)         // normal-feature low edge
#define ZLO_C (-14.2f)        // CRP-feature low edge (covers log(1e-6)=-13.8155)

#define PAIR_PTS  (NP * PT * PT)            // 7056
#define FEAT_PTS  (NF * FT)                 // 640
#define TOT_PTS   (PAIR_PTS + FEAT_PTS)     // 7696
#define PAIR_BYTES (PAIR_PTS * 8)           // 56448 (fp16 quads)
#define TAB_BYTES  (PAIR_BYTES + FEAT_PTS * 8) // 61568 (+ float2 feats)
#define TAB_VEC    (TAB_BYTES / 16)         // 3848 uint4s

// Branchless Abramowitz-Stegun 7.1.26 erf, abs err ~1e-6 in f32.
__device__ __forceinline__ float fast_erf(float v) {
    float ax = fabsf(v);
    float t  = __builtin_amdgcn_rcpf(fmaf(0.3275911f, ax, 1.0f));
    float p  = fmaf(1.061405429f, t, -1.453152027f);
    p = fmaf(p, t, 1.421413741f);
    p = fmaf(p, t, -0.284496736f);
    p = fmaf(p, t, 0.254829592f);
    p = p * t;
    float e = __expf(-ax * ax);
    float r = fmaf(-p, e, 1.0f);   // 1 - p*e
    return copysignf(r, v);
}

__device__ __forceinline__ float gelu_exact(float v) {
    return 0.5f * v * (1.0f + fast_erf(v * 0.70710678118654752f));
}

// ---- build both tables into one contiguous 61568-B ws buffer.
// layout: [ pair quads: half4 pq[p][i][j] ][ feat pairs: float2 fq[f][i] ]
// pq cell (p,i,j) = {v(i,j), v(i,j+1), v(i+1,j), v(i+1,j+1)} (fp16)
__global__ __launch_bounds__(256) void build_tabs(
    const float* __restrict__ w1f, const float* __restrict__ b1f,
    const float* __restrict__ w2f, const float* __restrict__ b2f,
    const float* __restrict__ w1p, const float* __restrict__ b1p,
    const float* __restrict__ w2p, const float* __restrict__ b2p,
    const int*  __restrict__ crpp,
    char* __restrict__ tab)
{
    int t = blockIdx.x * 256 + threadIdx.x;
    if (t >= TOT_PTS) return;
    const int crp = crpp[0];
    __half* pqh = (__half*)tab;
    float*  fqf = (float*)(tab + PAIR_BYTES);

    if (t < PAIR_PTS) {
        int p   = t / (PT * PT);
        int rem = t - p * (PT * PT);
        int i   = rem / PT;
        int j   = rem - i * PT;
        const float lo0 = (crp == 0)     ? ZLO_C : ZLO_N;
        const float lof = (p + 1 == crp) ? ZLO_C : ZLO_N;
        const float dz0 = (ZHI - lo0) / (float)(PT - 1);
        const float dzf = (ZHI - lof) / (float)(PT - 1);
        float z0 = lo0 + dz0 * (float)i;
        float zf = lof + dzf * (float)j;
        float s = b2p[p];
        #pragma unroll 8
        for (int h = 0; h < NH; ++h) {
            float a = w1p[(2 * p + 0) * NH + h];
            float b = w1p[(2 * p + 1) * NH + h];
            float u = fmaf(z0, a, fmaf(zf, b, b1p[p * NH + h]));
            s = fmaf(gelu_exact(u), w2p[p * NH + h], s);
        }
        __half hv = __float2half_rn(s);
        int cell = (p * PT + i) * PT + j;
        if (i <= PT - 2 && j <= PT - 2) pqh[4 * cell + 0]            = hv;
        if (i <= PT - 2 && j >= 1)      pqh[4 * (cell - 1) + 1]      = hv;
        if (i >= 1      && j <= PT - 2) pqh[4 * (cell - PT) + 2]     = hv;
        if (i >= 1      && j >= 1)      pqh[4 * (cell - PT - 1) + 3] = hv;
    } else {
        int u = t - PAIR_PTS;
        int f = u >> 6;
        int i = u & (FT - 1);
        const float lo = (f == crp) ? ZLO_C : ZLO_N;
        const float dz = (ZHI - lo) / (float)(FT - 1);
        float z = lo + dz * (float)i;
        float s = b2f[f];
        #pragma unroll 8
        for (int h = 0; h < NH; ++h) {
            float v = fmaf(z, w1f[f * NH + h], b1f[f * NH + h]);
            s = fmaf(gelu_exact(v), w2f[f * NH + h], s);
        }
        if (i <= FT - 2) fqf[2 * u + 0] = s;
        if (i >= 1)      fqf[2 * (u - 1) + 1] = s;
    }
}

// ---- main: stage tables into LDS, then per-row LDS lookups
__global__ __launch_bounds__(1024) void siarm_main(
    const float* __restrict__ x,
    const float* __restrict__ rmean, const float* __restrict__ rstd,
    const int*  __restrict__ crpp,
    const uint4* __restrict__ tab,
    float* __restrict__ out, int nrows)
{
    __shared__ uint4 lds[TAB_VEC];          // 61568 B
    const int tid = threadIdx.x;
    const int r = blockIdx.x * 1024 + tid;

    // issue stage loads first so they overlap the x-load + z-compute
    uint4 s0 = tab[tid];
    uint4 s1 = tab[tid + 1024];
    uint4 s2 = tab[tid + 2048];
    const bool g3 = tid < (TAB_VEC - 3072);  // 776
    uint4 s3;
    if (g3) s3 = tab[tid + 3072];

    const int crp = crpp[0];

    float raw[NF];
    {
        const float2* xr = reinterpret_cast<const float2*>(x + (size_t)r * NF);
        #pragma unroll
        for (int q = 0; q < NF / 2; ++q) {
            float2 v = xr[q];
            raw[2 * q] = v.x; raw[2 * q + 1] = v.y;
        }
    }

    float z[NF];
    #pragma unroll
    for (int f = 0; f < NF; ++f) {
        float rv = raw[f];
        if (f == crp) rv = __logf(fmaxf(rv * 10.0f, 1e-6f));
        z[f] = (rv - rmean[f]) * __builtin_amdgcn_rcpf(rstd[f]);
    }

    lds[tid]        = s0;
    lds[tid + 1024] = s1;
    lds[tid + 2048] = s2;
    if (g3) lds[tid + 3072] = s3;
    __syncthreads();

    if (r >= nrows) return;

    const uint2*  pq = reinterpret_cast<const uint2*>(lds);
    const float2* fq = reinterpret_cast<const float2*>(
                           reinterpret_cast<const char*>(lds) + PAIR_BYTES);

    float acc = 0.0f;

    // 1-D lookups
    const float invN1 = (float)(FT - 1) / (ZHI - ZLO_N);
    const float invC1 = (float)(FT - 1) / (ZHI - ZLO_C);
    #pragma unroll
    for (int f = 0; f < NF; ++f) {
        float lo  = (f == crp) ? ZLO_C : ZLO_N;
        float inv = (f == crp) ? invC1 : invN1;
        float c = fminf(fmaxf((z[f] - lo) * inv, 0.0f), (float)(FT - 2));
        float fi = floorf(c);
        float fr = c - fi;
        int i = (int)fi;
        float2 lh = fq[f * FT + i];
        acc += fmaf(fr, lh.y - lh.x, lh.x);
    }

    // 2-D bilinear lookups
    const float invN2 = (float)(PT - 1) / (ZHI - ZLO_N);
    const float invC2 = (float)(PT - 1) / (ZHI - ZLO_C);
    const float lo0   = (crp == 0) ? ZLO_C : ZLO_N;
    const float inv0  = (crp == 0) ? invC2 : invN2;
    float c0 = fminf(fmaxf((z[0] - lo0) * inv0, 0.0f), (float)(PT - 2));
    float f0 = floorf(c0);
    float fr0 = c0 - f0;
    int i0 = (int)f0;
    #pragma unroll
    for (int p = 0; p < NP; ++p) {
        float lof = (p + 1 == crp) ? ZLO_C : ZLO_N;
        float inv = (p + 1 == crp) ? invC2 : invN2;
        float cf = fminf(fmaxf((z[p + 1] - lof) * inv, 0.0f), (float)(PT - 2));
        float ff = floorf(cf);
        float frf = cf - ff;
        int jf = (int)ff;
        uint2 q = pq[(p * PT + i0) * PT + jf];
        __half2 ha = *reinterpret_cast<const __half2*>(&q.x);  // v00, v01
        __half2 hb = *reinterpret_cast<const __half2*>(&q.y);  // v10, v11
        float2 fa = __half22float2(ha);
        float2 fb = __half22float2(hb);
        float lov = fmaf(frf, fa.y - fa.x, fa.x);
        float hiv = fmaf(frf, fb.y - fb.x, fb.x);
        acc += fmaf(fr0, hiv - lov, lov);
    }

    out[r] = acc;
}

// ---- fallback: direct compute, used only if ws too small (never expected)
__global__ __launch_bounds__(256) void siarm_direct(
    const float* __restrict__ x,
    const float* __restrict__ rmean, const float* __restrict__ rstd,
    const float* __restrict__ w1f, const float* __restrict__ b1f,
    const float* __restrict__ w2f, const float* __restrict__ b2f,
    const float* __restrict__ w1p, const float* __restrict__ b1p,
    const float* __restrict__ w2p, const float* __restrict__ b2p,
    const int*  __restrict__ crpp,
    float* __restrict__ out, int nrows)
{
    int r = blockIdx.x * 256 + threadIdx.x;
    if (r >= nrows) return;
    const int crp = crpp[0];
    const size_t base = (size_t)r * NF;

    float raw0 = x[base + 0];
    if (crp == 0) raw0 = __logf(fmaxf(raw0 * 10.0f, 1e-6f));
    const float z0 = (raw0 - rmean[0]) / rstd[0];

    float acc = b2f[0];
    {
        float s = 0.0f;
        #pragma unroll 8
        for (int h = 0; h < NH; ++h) {
            float t = fmaf(z0, w1f[h], b1f[h]);
            s = fmaf(gelu_exact(t), w2f[h], s);
        }
        acc += s;
    }
    #pragma unroll 1
    for (int f = 1; f < NF; ++f) {
        float raw = x[base + f];
        if (f == crp) raw = __logf(fmaxf(raw * 10.0f, 1e-6f));
        const float zf = (raw - rmean[f]) / rstd[f];

        float sa = 0.0f;
        #pragma unroll 8
        for (int h = 0; h < NH; ++h) {
            float t = fmaf(zf, w1f[f * NH + h], b1f[f * NH + h]);
            sa = fmaf(gelu_exact(t), w2f[f * NH + h], sa);
        }
        const int p = f - 1;
        float sp = 0.0f;
        #pragma unroll 8
        for (int h = 0; h < NH; ++h) {
            float t = fmaf(z0, w1p[(2 * p) * NH + h],
                      fmaf(zf, w1p[(2 * p + 1) * NH + h], b1p[p * NH + h]));
            sp = fmaf(gelu_exact(t), w2p[p * NH + h], sp);
        }
        acc += sa + b2f[f] + sp + b2p[p];
    }
    out[r] = acc;
}

extern "C" void kernel_launch(void* const* d_in, const int* in_sizes, int n_in,
                              void* d_out, int out_size, void* d_ws, size_t ws_size,
                              hipStream_t stream) {
    const float* x     = (const float*)d_in[0];
    const float* rmean = (const float*)d_in[1];
    const float* rstd  = (const float*)d_in[2];
    const float* w1f   = (const float*)d_in[3];
    const float* b1f   = (const float*)d_in[4];
    const float* w2f   = (const float*)d_in[5];
    const float* b2f   = (const float*)d_in[6];
    const float* w1p   = (const float*)d_in[7];
    const float* b1p   = (const float*)d_in[8];
    const float* w2p   = (const float*)d_in[9];
    const float* b2p   = (const float*)d_in[10];
    const int*   crp   = (const int*)d_in[11];
    float* out = (float*)d_out;

    int nrows = out_size;

    if (ws_size >= (size_t)TAB_BYTES) {
        char* tab = (char*)d_ws;
        hipLaunchKernelGGL(build_tabs, dim3((TOT_PTS + 255) / 256), dim3(256), 0, stream,
                           w1f, b1f, w2f, b2f, w1p, b1p, w2p, b2p, crp, tab);
        hipLaunchKernelGGL(siarm_main, dim3((nrows + 1023) / 1024), dim3(1024), 0, stream,
                           x, rmean, rstd, crp, (const uint4*)tab, out, nrows);
    } else {
        hipLaunchKernelGGL(siarm_direct, dim3((nrows + 255) / 256), dim3(256), 0, stream,
                           x, rmean, rstd, w1f, b1f, w2f, b2f,
                           w1p, b1p, w2p, b2p, crp, out, nrows);
    }
}